// Round 11
// baseline (138.400 us; speedup 1.0000x reference)
//
#include <hip/hip_runtime.h>
#include <math.h>

#define J 25
#define NJC 75             // J * CIN
#define NWAVE 4            // waves per block
#define NTHREADS 256
#define NFPW 32            // frames per wave (persistent grid: 512 blocks)

// const-image layout (bf16 element offsets in CWS, per block in LDS)
#define O_A1P  0           // B for P2'', k32-permuted softmax(A1), 1024
#define O_APP  1024        // B for P4, k32-permuted, 1024
#define O_A4B  2048        // A/B for P7, k32-permuted, 1024
#define O_W2T  3072        // B for P3, k64-permuted, 2048
#define O_W3T  5120        // A for P5, k32-permuted, 2 M-tiles, 2048
#define O_W1A  7168        // B for P1', natural k=c-aug, [tile][half][n=d32][j8], 1024
#define O_W4C  8192        // B for P6, k64-permuted, [c][b][j], 256
#define O_B4   8512        // 4 floats (8 bf16 slots)
#define O_BPPF 8576        // 64 fp32 bias in C-reg order [g(4)][half(2)][jj(8)]
#define CWS_SZ 8704

using bf16x2 = __attribute__((ext_vector_type(2))) __bf16;
using bf16x8 = __attribute__((ext_vector_type(8))) __bf16;
using f32x4  = __attribute__((ext_vector_type(4))) float;
using f32x16 = __attribute__((ext_vector_type(16))) float;

__device__ inline bf16x8 zero8() {
    bf16x8 z;
    #pragma unroll
    for (int j = 0; j < 8; j++) z[j] = (__bf16)0.f;
    return z;
}

#if defined(__has_builtin)
#if __has_builtin(__builtin_amdgcn_cvt_pk_bf16_f32)
#define HAVE_PK_BF16 1
#endif
#endif

__device__ inline bf16x2 cvt2(float a, float b) {
#ifdef HAVE_PK_BF16
    return __builtin_amdgcn_cvt_pk_bf16_f32(a, b);
#else
    bf16x2 r; r[0] = (__bf16)a; r[1] = (__bf16)b; return r;
#endif
}
__device__ inline bf16x8 pk8(const f32x16& acc, int st) {
    const int b = 8 * st;
    bf16x8 r;
    #pragma unroll
    for (int p = 0; p < 4; p++) {
        bf16x2 v = cvt2(acc[b + 2 * p], acc[b + 2 * p + 1]);
        r[2 * p] = v[0]; r[2 * p + 1] = v[1];
    }
    return r;
}

// ---------------------------------------------------------------------------
// R11: SKEWED software pipeline on the R8 base (57us champion).
// Diagnosis: R8's 54% SIMD idle = 7 MFMA<->VALU boundary crossings per frame
// (acc drain before cvt_pk; VALU->MFMA srcA/B wait-states).  R10's lockstep
// ILP x2 was null because both frames hit the SAME stage -> hazard windows
// ALIGN; nothing fills them (MfmaUtil scaled exactly with 1/dur).  Skewing
// by half a pipeline de-correlates the windows: front(f) = P1'->P2''->P3
// interleaved with back(f-1) = P4->P5->P6->P7+store.  Loop-carried state is
// just uf (8 VGPRs).  When back drains, front has ready MFMAs (inputs made
// last iteration) and vice versa.  Peak ~4 live f32x16 accs, total ~243
// regs < 256; stays 2 waves/SIMD.  Grid/data path identical to R8
// (persistent 512 blocks, NFPW=32, rB16 persistent C-in, swapped P7).
// ---------------------------------------------------------------------------
__global__ __launch_bounds__(NTHREADS, 2) void gcn_fused(
    const float* __restrict__ x,
    const float* __restrict__ A1, const float* __restrict__ W1, const float* __restrict__ b1,
    const float* __restrict__ A2, const float* __restrict__ W2, const float* __restrict__ b2,
    const float* __restrict__ A3, const float* __restrict__ W3, const float* __restrict__ b3,
    const float* __restrict__ A4, const float* __restrict__ W4, const float* __restrict__ b4,
    float* __restrict__ out)
{
    __shared__ __align__(16) float  TS[3189];            // prologue scratch
    __shared__ __align__(16) __bf16 CWS[CWS_SZ];         // 17408 B

    const int t = threadIdx.x;

    // ================= per-block prologue: const image into CWS ===========
    {
        float* T   = TS;
        float* bpp = T + 3125;
        float* T0 = T;        float* T1 = T + 625;  float* T2 = T + 1250;
        float* T3 = T + 1875; float* T4 = T + 2500;

        if (t < 100) {
            const int m = t / J, i = t % J;
            const float* Asrc = (m == 0) ? A1 : (m == 1) ? A2 : (m == 2) ? A3 : A4;
            float row[J];
            float mx = -1e30f;
            #pragma unroll
            for (int j = 0; j < J; j++) { row[j] = Asrc[i * J + j]; mx = fmaxf(mx, row[j]); }
            float s = 0.f;
            #pragma unroll
            for (int j = 0; j < J; j++) { row[j] = __expf(row[j] - mx); s += row[j]; }
            const float inv = 1.f / s;
            float* dst = T + m * 625 + i * J;
            #pragma unroll
            for (int j = 0; j < J; j++) dst[j] = row[j] * inv;
        }
        if (t < 64) {                                      // bpp = W3^T b2 + b3
            float s = b3[t];
            #pragma unroll
            for (int l = 0; l < 32; l++) s += W3[l * 64 + t] * b2[l];
            bpp[t] = s;
        }
        __syncthreads();

        for (int idx = t; idx < 625; idx += 256) {        // App = A3s @ A2s
            const int i = idx / J, jj = idx % J;
            float s = 0.f;
            #pragma unroll
            for (int k = 0; k < J; k++) s += T2[i * J + k] * T1[k * J + jj];
            T4[idx] = s;
        }
        __syncthreads();

        // ---- A1P, App, A4b (all k32-permuted) ----
        for (int i = t; i < 1024; i += 256) {
            const int b = i >> 8, n = (i >> 3) & 31, jj = i & 7;
            const int s = b >> 1, h = b & 1, r = 8 * s + jj;
            const int k32 = (r & 3) + 8 * (r >> 2) + 4 * h;
            const bool ok = (k32 < J && n < J);
            CWS[O_A1P + i] = (__bf16)(ok ? T0[n * J + k32] : 0.f);
            CWS[O_APP + i] = (__bf16)(ok ? T4[n * J + k32] : 0.f);
            CWS[O_A4B + i] = (__bf16)(ok ? T3[n * J + k32] : 0.f);
        }
        // ---- W2T (k64-perm) | W3T (k32-perm, 2 tiles) ----
        for (int i = t; i < 2048; i += 256) {
            {
                const int b = i >> 8, n = (i >> 3) & 31, jj = i & 7;
                const int s = b >> 1, h = b & 1, r = 8 * (s & 1) + jj;
                const int d = 32 * (s >> 1) + (r & 3) + 8 * (r >> 2) + 4 * h;
                CWS[O_W2T + i] = (__bf16)W2[d * 32 + n];
            }
            {
                const int tt = i >> 10, rr = i & 1023;
                const int b = rr >> 8, m = (rr >> 3) & 31, jj = rr & 7;
                const int s = b >> 1, h = b & 1, r = 8 * s + jj;
                const int l = (r & 3) + 8 * (r >> 2) + 4 * h;
                CWS[O_W3T + i] = (__bf16)W3[l * 64 + tt * 32 + m];
            }
        }
        // ---- W1A (B for P1'): [tile][half][n=d32][j8], k = 8*half+j natural;
        //      k<3 -> W1[k][d]; k==3 -> b1[d]; else 0 ----
        for (int i = t; i < 1024; i += 256) {
            const int tile = i >> 9, rr = i & 511, hf_ = rr >> 8, n = (rr >> 3) & 31, jj = rr & 7;
            const int k = 8 * hf_ + jj;
            const int d = tile * 32 + n;
            float v = 0.f;
            if (k < 3) v = W1[k * 64 + d];
            else if (k == 3) v = b1[d];
            CWS[O_W1A + i] = (__bf16)v;
        }
        // ---- W4c (k64-perm): [c][b][j] = W4[d64][c] ----
        {
            const int c = t >> 6, b = (t >> 3) & 7, jj = t & 7;
            const int s = b >> 1, h = b & 1, r = 8 * (s & 1) + jj;
            const int d = 32 * (s >> 1) + (r & 3) + 8 * (r >> 2) + 4 * h;
            CWS[O_W4C + t] = (c < 3) ? (__bf16)W4[d * 3 + c] : (__bf16)0.f;
        }
        // ---- fp32 bias tables ----
        {
            float* fwB = (float*)(CWS + O_BPPF);
            if (t < 64) {
                const int g = t >> 4, h = (t >> 3) & 1, jj = t & 7;
                const int tt = g >> 1, st = g & 1;
                const int row32 = (jj & 3) + 16 * st + 8 * (jj >> 2) + 4 * h;
                fwB[t] = bpp[tt * 32 + row32];
            }
            float* fb4 = (float*)(CWS + O_B4);
            if (t >= 64 && t < 68) fb4[t - 64] = (t < 67) ? b4[t - 64] : 0.f;
        }
        __syncthreads();   // CWS final
    }

    // ================= main fused pipeline ================================
    const int w = t >> 6, lane = t & 63, ln = lane & 31, half = lane >> 5;
    const int fo = ln * 8;

    const long fbase = ((long)blockIdx.x * NWAVE + w) * NFPW;

    // wave-uniform scalar base pointers (advanced per frame on SALU)
    const float* xp = x + fbase * NJC;        // next frame to LOAD from
    float* op = out + fbase * NJC;            // back-stream output base

    const bool xact = (lane < J);             // X-load lanes (implies half0)
    const int xoff = lane * 3;

    // ---- load frame 0 into xCur regs
    float xc0 = 0.f, xc1 = 0.f, xc2 = 0.f;
    if (xact) {
        const float* q = xp + xoff;
        xc0 = q[0]; xc1 = q[1]; xc2 = q[2];
    }
    xp += NJC;

    // ---- persistent register frags
    bf16x8 rA1P[2], rApp[2], rA4b[2], rW1A[2], rW2[4], rW3[4], rW4[4];
    #pragma unroll
    for (int ks = 0; ks < 2; ks++) {
        rA1P[ks] = *(const bf16x8*)&CWS[O_A1P + (2 * ks + half) * 256 + fo];
        rApp[ks] = *(const bf16x8*)&CWS[O_APP + (2 * ks + half) * 256 + fo];
        rA4b[ks] = *(const bf16x8*)&CWS[O_A4B + (2 * ks + half) * 256 + fo];
        rW1A[ks] = *(const bf16x8*)&CWS[O_W1A + ks * 512 + half * 256 + fo];
    }
    #pragma unroll
    for (int ks = 0; ks < 4; ks++)
        rW2[ks] = *(const bf16x8*)&CWS[O_W2T + (half + 2 * ks) * 256 + fo];
    #pragma unroll
    for (int tt = 0; tt < 2; tt++)
        #pragma unroll
        for (int ks = 0; ks < 2; ks++)
            rW3[tt * 2 + ks] = *(const bf16x8*)&CWS[O_W3T + tt * 1024 + (half + 2 * ks) * 256 + fo];
    #pragma unroll
    for (int ks = 0; ks < 4; ks++) {
        rW4[ks] = zero8();
        if (ln < 3) rW4[ks] = *(const bf16x8*)&CWS[O_W4C + ln * 64 + (half + 2 * ks) * 8];
    }
    // P5 bias as MFMA C-operand, C layout (persistent, R5/R8-proven)
    f32x16 rB16[2];
    {
        const float* fwB = (const float*)(CWS + O_BPPF);
        #pragma unroll
        for (int tt = 0; tt < 2; tt++)
            #pragma unroll
            for (int st = 0; st < 2; st++) {
                f32x4 qa = *(const f32x4*)&fwB[32 * tt + 16 * st + 8 * half + 0];
                f32x4 qb = *(const f32x4*)&fwB[32 * tt + 16 * st + 8 * half + 4];
                #pragma unroll
                for (int j = 0; j < 4; j++) {
                    rB16[tt][8 * st + j]     = qa[j];
                    rB16[tt][8 * st + 4 + j] = qb[j];
                }
            }
    }
    // b4 as 3 wave-uniform floats (LDS broadcast; plain loads -- R6 lesson:
    // never pass floats through the i32-typed readfirstlane builtin)
    const float* fb4 = (const float*)(CWS + O_B4);
    const float b40 = fb4[0], b41 = fb4[1], b42 = fb4[2];

    // ---- shared zero accumulator (MFMA allows D != C)
    f32x16 Z;
    #pragma unroll
    for (int z = 0; z < 16; z++) Z[z] = 0.f;

    const bool do_store = (lane < J);   // loop-invariant store mask (half0 only)

    // ---- loop-carried: uf of the frame currently between front and back
    bf16x8 ufP0, ufP1;

    // ================= PIPELINE PROLOGUE: front(frame 0) ==================
    {
        bf16x8 xa = zero8();
        if (xact) {
            xa[0] = (__bf16)xc0; xa[1] = (__bf16)xc1;
            xa[2] = (__bf16)xc2; xa[3] = (__bf16)1.f;
        }
        // load frame 1
        if (xact) {
            const float* q = xp + xoff;
            xc0 = q[0]; xc1 = q[1]; xc2 = q[2];
        }
        xp += NJC;

        f32x16 accG0 = __builtin_amdgcn_mfma_f32_32x32x16_bf16(xa, rW1A[0], Z, 0, 0, 0);
        f32x16 accG1 = __builtin_amdgcn_mfma_f32_32x32x16_bf16(xa, rW1A[1], Z, 0, 0, 0);
        bf16x8 ga0 = pk8(accG0, 0), ga1 = pk8(accG0, 1);
        bf16x8 ga2 = pk8(accG1, 0), ga3 = pk8(accG1, 1);

        f32x16 accH0 = __builtin_amdgcn_mfma_f32_32x32x16_bf16(ga0, rA1P[0], Z, 0, 0, 0);
        accH0 = __builtin_amdgcn_mfma_f32_32x32x16_bf16(ga1, rA1P[1], accH0, 0, 0, 0);
        f32x16 accH1 = __builtin_amdgcn_mfma_f32_32x32x16_bf16(ga2, rA1P[0], Z, 0, 0, 0);
        accH1 = __builtin_amdgcn_mfma_f32_32x32x16_bf16(ga3, rA1P[1], accH1, 0, 0, 0);
        #pragma unroll
        for (int z = 0; z < 16; z++) {
            accH0[z] = fmaxf(accH0[z], 0.f);
            accH1[z] = fmaxf(accH1[z], 0.f);
        }
        bf16x8 hf0 = pk8(accH0, 0), hf1 = pk8(accH0, 1);
        bf16x8 hf2 = pk8(accH1, 0), hf3 = pk8(accH1, 1);

        f32x16 accU = __builtin_amdgcn_mfma_f32_32x32x16_bf16(hf0, rW2[0], Z, 0, 0, 0);
        accU = __builtin_amdgcn_mfma_f32_32x32x16_bf16(hf1, rW2[1], accU, 0, 0, 0);
        accU = __builtin_amdgcn_mfma_f32_32x32x16_bf16(hf2, rW2[2], accU, 0, 0, 0);
        accU = __builtin_amdgcn_mfma_f32_32x32x16_bf16(hf3, rW2[3], accU, 0, 0, 0);
        ufP0 = pk8(accU, 0); ufP1 = pk8(accU, 1);
    }

    // ================= STEADY STATE: back(fi-1) ∥ front(fi) ==============
    #pragma unroll 1
    for (int fi = 1; fi < NFPW; fi++) {
        // pack current frame's xa (VALU, independent of both streams)
        bf16x8 xa = zero8();
        if (xact) {
            xa[0] = (__bf16)xc0; xa[1] = (__bf16)xc1;
            xa[2] = (__bf16)xc2; xa[3] = (__bf16)1.f;
        }
        // load frame fi+1 (overwrite after use; 1-frame distance >> latency)
        if (fi + 1 < NFPW && xact) {
            const float* q = xp + xoff;
            xc0 = q[0]; xc1 = q[1]; xc2 = q[2];
        }
        xp += NJC;

        // -- back.P4 start (uses loop-carried ufP) + front.P1' interleaved
        f32x16 accV = __builtin_amdgcn_mfma_f32_32x32x16_bf16(ufP0, rApp[0], Z, 0, 0, 0);
        f32x16 accG0 = __builtin_amdgcn_mfma_f32_32x32x16_bf16(xa, rW1A[0], Z, 0, 0, 0);
        accV = __builtin_amdgcn_mfma_f32_32x32x16_bf16(ufP1, rApp[1], accV, 0, 0, 0);
        f32x16 accG1 = __builtin_amdgcn_mfma_f32_32x32x16_bf16(xa, rW1A[1], Z, 0, 0, 0);

        // -- back: pack vf (accV drain hidden under P1' issue)
        bf16x8 vf0 = pk8(accV, 0), vf1 = pk8(accV, 1);

        // -- back.P5 (4 MFMAs; bias as C-in)
        f32x16 acc50 = __builtin_amdgcn_mfma_f32_32x32x16_bf16(rW3[0], vf0, rB16[0], 0, 0, 0);
        f32x16 acc51 = __builtin_amdgcn_mfma_f32_32x32x16_bf16(rW3[2], vf0, rB16[1], 0, 0, 0);
        acc50 = __builtin_amdgcn_mfma_f32_32x32x16_bf16(rW3[1], vf1, acc50, 0, 0, 0);
        acc51 = __builtin_amdgcn_mfma_f32_32x32x16_bf16(rW3[3], vf1, acc51, 0, 0, 0);

        // -- front: pack ga (accG drain hidden under P5 issue)
        bf16x8 ga0 = pk8(accG0, 0), ga1 = pk8(accG0, 1);
        bf16x8 ga2 = pk8(accG1, 0), ga3 = pk8(accG1, 1);

        // -- front.P2'' (4 MFMAs)
        f32x16 accH0 = __builtin_amdgcn_mfma_f32_32x32x16_bf16(ga0, rA1P[0], Z, 0, 0, 0);
        accH0 = __builtin_amdgcn_mfma_f32_32x32x16_bf16(ga1, rA1P[1], accH0, 0, 0, 0);
        f32x16 accH1 = __builtin_amdgcn_mfma_f32_32x32x16_bf16(ga2, rA1P[0], Z, 0, 0, 0);
        accH1 = __builtin_amdgcn_mfma_f32_32x32x16_bf16(ga3, rA1P[1], accH1, 0, 0, 0);

        // -- back: relu + pack hd (acc5 drain hidden under P2'' issue)
        #pragma unroll
        for (int z = 0; z < 16; z++) {
            acc50[z] = fmaxf(acc50[z], 0.f);
            acc51[z] = fmaxf(acc51[z], 0.f);
        }
        bf16x8 hd0 = pk8(acc50, 0), hd1 = pk8(acc50, 1);
        bf16x8 hd2 = pk8(acc51, 0), hd3 = pk8(acc51, 1);

        // -- back.P6 (4 MFMAs)
        f32x16 accP = __builtin_amdgcn_mfma_f32_32x32x16_bf16(hd0, rW4[0], Z, 0, 0, 0);
        accP = __builtin_amdgcn_mfma_f32_32x32x16_bf16(hd1, rW4[1], accP, 0, 0, 0);
        accP = __builtin_amdgcn_mfma_f32_32x32x16_bf16(hd2, rW4[2], accP, 0, 0, 0);
        accP = __builtin_amdgcn_mfma_f32_32x32x16_bf16(hd3, rW4[3], accP, 0, 0, 0);

        // -- front: relu + pack hf (accH drain hidden under P6 issue)
        #pragma unroll
        for (int z = 0; z < 16; z++) {
            accH0[z] = fmaxf(accH0[z], 0.f);
            accH1[z] = fmaxf(accH1[z], 0.f);
        }
        bf16x8 hf0 = pk8(accH0, 0), hf1 = pk8(accH0, 1);
        bf16x8 hf2 = pk8(accH1, 0), hf3 = pk8(accH1, 1);

        // -- front.P3 (4 MFMAs)
        f32x16 accU = __builtin_amdgcn_mfma_f32_32x32x16_bf16(hf0, rW2[0], Z, 0, 0, 0);
        accU = __builtin_amdgcn_mfma_f32_32x32x16_bf16(hf1, rW2[1], accU, 0, 0, 0);
        accU = __builtin_amdgcn_mfma_f32_32x32x16_bf16(hf2, rW2[2], accU, 0, 0, 0);
        accU = __builtin_amdgcn_mfma_f32_32x32x16_bf16(hf3, rW2[3], accU, 0, 0, 0);

        // -- back: pack pf (accP drain hidden under P3 issue)
        bf16x8 pf0 = pk8(accP, 0), pf1 = pk8(accP, 1);

        // -- back.P7 (2 MFMAs, swapped)
        f32x16 accO = __builtin_amdgcn_mfma_f32_32x32x16_bf16(pf0, rA4b[0], Z, 0, 0, 0);
        accO = __builtin_amdgcn_mfma_f32_32x32x16_bf16(pf1, rA4b[1], accO, 0, 0, 0);

        // -- front: pack uf -> loop-carried (accU drain hidden under P7)
        ufP0 = pk8(accU, 0); ufP1 = pk8(accU, 1);

        // -- back: store frame fi-1
        if (do_store) {
            op[lane * 3 + 0] = accO[0] + b40;
            op[lane * 3 + 1] = accO[1] + b41;
            op[lane * 3 + 2] = accO[2] + b42;
        }
        op += NJC;
    }

    // ================= PIPELINE EPILOGUE: back(frame NFPW-1) =============
    {
        f32x16 accV = __builtin_amdgcn_mfma_f32_32x32x16_bf16(ufP0, rApp[0], Z, 0, 0, 0);
        accV = __builtin_amdgcn_mfma_f32_32x32x16_bf16(ufP1, rApp[1], accV, 0, 0, 0);
        bf16x8 vf0 = pk8(accV, 0), vf1 = pk8(accV, 1);

        f32x16 acc50 = __builtin_amdgcn_mfma_f32_32x32x16_bf16(rW3[0], vf0, rB16[0], 0, 0, 0);
        acc50 = __builtin_amdgcn_mfma_f32_32x32x16_bf16(rW3[1], vf1, acc50, 0, 0, 0);
        f32x16 acc51 = __builtin_amdgcn_mfma_f32_32x32x16_bf16(rW3[2], vf0, rB16[1], 0, 0, 0);
        acc51 = __builtin_amdgcn_mfma_f32_32x32x16_bf16(rW3[3], vf1, acc51, 0, 0, 0);
        #pragma unroll
        for (int z = 0; z < 16; z++) {
            acc50[z] = fmaxf(acc50[z], 0.f);
            acc51[z] = fmaxf(acc51[z], 0.f);
        }
        bf16x8 hd0 = pk8(acc50, 0), hd1 = pk8(acc50, 1);
        bf16x8 hd2 = pk8(acc51, 0), hd3 = pk8(acc51, 1);

        f32x16 accP = __builtin_amdgcn_mfma_f32_32x32x16_bf16(hd0, rW4[0], Z, 0, 0, 0);
        accP = __builtin_amdgcn_mfma_f32_32x32x16_bf16(hd1, rW4[1], accP, 0, 0, 0);
        accP = __builtin_amdgcn_mfma_f32_32x32x16_bf16(hd2, rW4[2], accP, 0, 0, 0);
        accP = __builtin_amdgcn_mfma_f32_32x32x16_bf16(hd3, rW4[3], accP, 0, 0, 0);
        bf16x8 pf0 = pk8(accP, 0), pf1 = pk8(accP, 1);

        f32x16 accO = __builtin_amdgcn_mfma_f32_32x32x16_bf16(pf0, rA4b[0], Z, 0, 0, 0);
        accO = __builtin_amdgcn_mfma_f32_32x32x16_bf16(pf1, rA4b[1], accO, 0, 0, 0);
        if (do_store) {
            op[lane * 3 + 0] = accO[0] + b40;
            op[lane * 3 + 1] = accO[1] + b41;
            op[lane * 3 + 2] = accO[2] + b42;
        }
    }
}

// ---------------------------------------------------------------------------
extern "C" void kernel_launch(void* const* d_in, const int* in_sizes, int n_in,
                              void* d_out, int out_size, void* d_ws, size_t ws_size,
                              hipStream_t stream)
{
    const float* x  = (const float*)d_in[0];
    const float* A1 = (const float*)d_in[1];
    const float* W1 = (const float*)d_in[2];
    const float* b1 = (const float*)d_in[3];
    const float* A2 = (const float*)d_in[4];
    const float* W2 = (const float*)d_in[5];
    const float* b2 = (const float*)d_in[6];
    const float* A3 = (const float*)d_in[7];
    const float* W3 = (const float*)d_in[8];
    const float* b3 = (const float*)d_in[9];
    const float* A4 = (const float*)d_in[10];
    const float* W4 = (const float*)d_in[11];
    const float* b4 = (const float*)d_in[12];
    float* out = (float*)d_out;
    (void)d_ws; (void)ws_size;

    const int NT = in_sizes[0] / NJC;                 // 65536
    const int nblocks = NT / (NWAVE * NFPW);          // 512 = 2 blocks/CU

    gcn_fused<<<nblocks, NTHREADS, 0, stream>>>(
        x, A1, W1, b1, A2, W2, b2, A3, W3, b3, A4, W4, b4, out);
}